// Round 17
// baseline (162.254 us; speedup 1.0000x reference)
//
#include <hip/hip_runtime.h>
#include <hip/hip_bf16.h>
#include <math.h>

#define D_MODEL 1024
#define N_HEADS 16
#define D_HEAD  64
#define SEQ     2048
#define NBATCH  2
#define NROWS   (NBATCH * SEQ)      // 4096

#define C2F 0.18033688011112042f    // 0.125 * log2(e), folded into Q weights/bias

typedef __attribute__((ext_vector_type(8))) short short8v;        // 8 bf16
typedef __attribute__((ext_vector_type(4))) float f32x4;
typedef __attribute__((ext_vector_type(16))) float f32x16;
typedef __attribute__((ext_vector_type(4))) unsigned int u32x4;

__device__ __forceinline__ unsigned short f2bf(float x) {
    unsigned int u = __float_as_uint(x);
    return (unsigned short)((u + 0x7FFFu + ((u >> 16) & 1u)) >> 16);   // RNE
}
// truncation split: hi = top-16-bits of fp32, lo = RNE(x - hi)
__device__ __forceinline__ void split_bf(float x, unsigned short& hi, unsigned short& lo) {
    unsigned int u = __float_as_uint(x);
    unsigned int ht = u & 0xFFFF0000u;
    hi = (unsigned short)(ht >> 16);
    lo = f2bf(x - __uint_as_float(ht));
}
// packed RNE f32x2 -> bf16x2
__device__ __forceinline__ unsigned int cvtpk(float lo, float hi) {
    unsigned int r;
    asm("v_cvt_pk_bf16_f32 %0, %1, %2" : "=v"(r) : "v"(lo), "v"(hi));
    return r;
}
__device__ __forceinline__ short8v u2s(u32x4 v) {
    union { u32x4 u; short8v s; } c; c.u = v; return c.s;
}

// ---------------------------------------------------------------------------
// Weight transpose + split: W[K][N] fp32 -> Th[N][K] (+ Tl[N][K] if write_lo).
// Columns n < qcols pre-scaled by C2F. write_lo=0 -> Th is RNE-rounded.
// ---------------------------------------------------------------------------
__global__ __launch_bounds__(256) void splitT_kernel(
    const float* __restrict__ W, unsigned short* __restrict__ Th,
    unsigned short* __restrict__ Tl, int K, int N, int qcols, int write_lo)
{
    __shared__ float tile[64][68];
    const int tid = threadIdx.x;
    const int nbn = N >> 6;
    const int k0 = (blockIdx.x / nbn) << 6;
    const int n0 = (blockIdx.x % nbn) << 6;
    const int r  = tid >> 4;
    const int c4 = (tid & 15) * 4;

#pragma unroll
    for (int i = 0; i < 4; ++i) {
        float4 v = *(const float4*)(W + (size_t)(k0 + r + i * 16) * N + n0 + c4);
        *(float4*)&tile[r + i * 16][c4] = v;
    }
    __syncthreads();

    const int kl = (tid & 15) * 4;
#pragma unroll
    for (int i = 0; i < 4; ++i) {
        const int nl = (tid >> 4) + i * 16;
        const float sc = (n0 + nl < qcols) ? C2F : 1.0f;
        if (write_lo) {
            ushort4 h4, l4;
            unsigned short h, l;
            split_bf(tile[kl + 0][nl] * sc, h, l); h4.x = h; l4.x = l;
            split_bf(tile[kl + 1][nl] * sc, h, l); h4.y = h; l4.y = l;
            split_bf(tile[kl + 2][nl] * sc, h, l); h4.z = h; l4.z = l;
            split_bf(tile[kl + 3][nl] * sc, h, l); h4.w = h; l4.w = l;
            *(ushort4*)(Th + (size_t)(n0 + nl) * K + k0 + kl) = h4;
            *(ushort4*)(Tl + (size_t)(n0 + nl) * K + k0 + kl) = l4;
        } else {
            ushort4 h4;
            h4.x = f2bf(tile[kl + 0][nl] * sc);
            h4.y = f2bf(tile[kl + 1][nl] * sc);
            h4.z = f2bf(tile[kl + 2][nl] * sc);
            h4.w = f2bf(tile[kl + 3][nl] * sc);
            *(ushort4*)(Th + (size_t)(n0 + nl) * K + k0 + kl) = h4;
        }
    }
}

// ---------------------------------------------------------------------------
// GEMM1 (1-term bf16): qkv[M,N](bf16) = RNE_bf16(A) @ Bh[N,K]^T + bias.
// ---------------------------------------------------------------------------
#define ASTRIDE 40    // bf16 elems; 80B row stride

__global__ __launch_bounds__(256) void gemm_xw_kernel(
    const float* __restrict__ A,
    const unsigned short* __restrict__ Bth,
    const float* __restrict__ bias,
    unsigned short* __restrict__ C, int M, int N, int K, int qcols)
{
    __shared__ __align__(16) unsigned short Ab[128][ASTRIDE];
    __shared__ __align__(16) unsigned short Bh[128][ASTRIDE];

    const int tid  = threadIdx.x;
    const int wave = tid >> 6;
    const int lane = tid & 63;
    const int col  = lane & 15;
    const int q4   = lane >> 4;
    const int wm   = (wave >> 1) * 64;
    const int wn   = (wave & 1) * 64;

    const int nwg = gridDim.x;
    const int cpx = nwg >> 3;
    const int swz = (blockIdx.x & 7) * cpx + (blockIdx.x >> 3);
    const int nbn = N / 128;
    const int bm = (swz / nbn) * 128;
    const int bn = (swz % nbn) * 128;

    const int sr = tid >> 1;
    const int sq = (tid & 1) * 16;
    const float* aptr = A + (size_t)(bm + sr) * K + sq;
    const unsigned short* bhp = Bth + (size_t)(bn + sr) * K + sq;

    f32x4 acc[4][4];
#pragma unroll
    for (int i = 0; i < 4; ++i)
#pragma unroll
        for (int j = 0; j < 4; ++j) acc[i][j] = (f32x4){0.f, 0.f, 0.f, 0.f};

    float4 a0, a1, a2, a3;
    short8v b0h, b1h;

#define G1LOAD(k0) { \
    a0 = *(const float4*)(aptr + (k0)); \
    a1 = *(const float4*)(aptr + (k0) + 4); \
    a2 = *(const float4*)(aptr + (k0) + 8); \
    a3 = *(const float4*)(aptr + (k0) + 12); \
    b0h = *(const short8v*)(bhp + (k0)); \
    b1h = *(const short8v*)(bhp + (k0) + 8); \
}

#define G1WRITE() { \
    u32x4 p0, p1; \
    p0.x = cvtpk(a0.x, a0.y); p0.y = cvtpk(a0.z, a0.w); \
    p0.z = cvtpk(a1.x, a1.y); p0.w = cvtpk(a1.z, a1.w); \
    p1.x = cvtpk(a2.x, a2.y); p1.y = cvtpk(a2.z, a2.w); \
    p1.z = cvtpk(a3.x, a3.y); p1.w = cvtpk(a3.z, a3.w); \
    *(u32x4*)&Ab[sr][sq]     = p0; \
    *(u32x4*)&Ab[sr][sq + 8] = p1; \
    *(short8v*)&Bh[sr][sq]     = b0h; \
    *(short8v*)&Bh[sr][sq + 8] = b1h; \
}

#define G1COMP() { \
    short8v af[4]; \
    _Pragma("unroll") \
    for (int mt = 0; mt < 4; ++mt) \
        af[mt] = *(const short8v*)&Ab[wm + mt * 16 + col][q4 * 8]; \
    _Pragma("unroll") \
    for (int nt = 0; nt < 4; ++nt) { \
        short8v bhf = *(const short8v*)&Bh[wn + nt * 16 + col][q4 * 8]; \
        _Pragma("unroll") \
        for (int mt = 0; mt < 4; ++mt) \
            acc[mt][nt] = __builtin_amdgcn_mfma_f32_16x16x32_bf16(af[mt], bhf, acc[mt][nt], 0, 0, 0); \
    } \
}

    G1LOAD(0);
    G1WRITE();
    for (int k0 = 32; k0 < K; k0 += 32) {
        G1LOAD(k0);
        __syncthreads();
        G1COMP();
        __syncthreads();
        G1WRITE();
    }
    __syncthreads();
    G1COMP();
#undef G1LOAD
#undef G1WRITE
#undef G1COMP

    const float bscale = (bn < qcols) ? C2F : 1.0f;
    float bv[4];
#pragma unroll
    for (int nt = 0; nt < 4; ++nt) bv[nt] = bias[bn + wn + nt * 16 + col] * bscale;

#pragma unroll
    for (int mt = 0; mt < 4; ++mt)
#pragma unroll
        for (int r = 0; r < 4; ++r) {
            const int row = bm + wm + mt * 16 + q4 * 4 + r;
#pragma unroll
            for (int nt = 0; nt < 4; ++nt)
                C[(size_t)row * N + bn + wn + nt * 16 + col] = f2bf(acc[mt][nt][r] + bv[nt]);
        }
}

// ---------------------------------------------------------------------------
// GEMM2: out[M,N](fp32) = (Aoh+Aol)[M,K] @ (Bh+Bl)[N,K]^T + bias, 3-term.
// ---------------------------------------------------------------------------
__global__ __launch_bounds__(256) void gemm_ao_kernel(
    const unsigned short* __restrict__ Aoh,
    const unsigned short* __restrict__ Aol,
    const unsigned short* __restrict__ Bth,
    const unsigned short* __restrict__ Btl,
    const float* __restrict__ bias,
    float* __restrict__ C, int M, int N, int K)
{
    __shared__ __align__(16) unsigned short Ah[128][ASTRIDE];
    __shared__ __align__(16) unsigned short Al[128][ASTRIDE];
    __shared__ __align__(16) unsigned short Bh[128][ASTRIDE];
    __shared__ __align__(16) unsigned short Bl[128][ASTRIDE];

    const int tid  = threadIdx.x;
    const int wave = tid >> 6;
    const int lane = tid & 63;
    const int col  = lane & 15;
    const int q4   = lane >> 4;
    const int wm   = (wave >> 1) * 64;
    const int wn   = (wave & 1) * 64;

    const int nwg = gridDim.x;
    const int cpx = nwg >> 3;
    const int swz = (blockIdx.x & 7) * cpx + (blockIdx.x >> 3);
    const int nbn = N / 128;
    const int bm = (swz / nbn) * 128;
    const int bn = (swz % nbn) * 128;

    const int sr = tid >> 1;
    const int sq = (tid & 1) * 16;
    const unsigned short* ahp = Aoh + (size_t)(bm + sr) * K + sq;
    const unsigned short* alp = Aol + (size_t)(bm + sr) * K + sq;
    const unsigned short* bhp = Bth + (size_t)(bn + sr) * K + sq;
    const unsigned short* blp = Btl + (size_t)(bn + sr) * K + sq;

    f32x4 acc[4][4];
#pragma unroll
    for (int i = 0; i < 4; ++i)
#pragma unroll
        for (int j = 0; j < 4; ++j) acc[i][j] = (f32x4){0.f, 0.f, 0.f, 0.f};

    short8v a0h, a1h, a0l, a1l, b0h, b1h, b0l, b1l;

#define G2LOAD(k0) { \
    a0h = *(const short8v*)(ahp + (k0)); \
    a1h = *(const short8v*)(ahp + (k0) + 8); \
    a0l = *(const short8v*)(alp + (k0)); \
    a1l = *(const short8v*)(alp + (k0) + 8); \
    b0h = *(const short8v*)(bhp + (k0)); \
    b1h = *(const short8v*)(bhp + (k0) + 8); \
    b0l = *(const short8v*)(blp + (k0)); \
    b1l = *(const short8v*)(blp + (k0) + 8); \
}

#define G2WRITE() { \
    *(short8v*)&Ah[sr][sq]     = a0h; \
    *(short8v*)&Ah[sr][sq + 8] = a1h; \
    *(short8v*)&Al[sr][sq]     = a0l; \
    *(short8v*)&Al[sr][sq + 8] = a1l; \
    *(short8v*)&Bh[sr][sq]     = b0h; \
    *(short8v*)&Bh[sr][sq + 8] = b1h; \
    *(short8v*)&Bl[sr][sq]     = b0l; \
    *(short8v*)&Bl[sr][sq + 8] = b1l; \
}

#define G2COMP() { \
    short8v ahf[4], alf[4]; \
    _Pragma("unroll") \
    for (int mt = 0; mt < 4; ++mt) { \
        ahf[mt] = *(const short8v*)&Ah[wm + mt * 16 + col][q4 * 8]; \
        alf[mt] = *(const short8v*)&Al[wm + mt * 16 + col][q4 * 8]; \
    } \
    _Pragma("unroll") \
    for (int nt = 0; nt < 4; ++nt) { \
        short8v bhf = *(const short8v*)&Bh[wn + nt * 16 + col][q4 * 8]; \
        short8v blf = *(const short8v*)&Bl[wn + nt * 16 + col][q4 * 8]; \
        _Pragma("unroll") \
        for (int mt = 0; mt < 4; ++mt) { \
            acc[mt][nt] = __builtin_amdgcn_mfma_f32_16x16x32_bf16(ahf[mt], bhf, acc[mt][nt], 0, 0, 0); \
            acc[mt][nt] = __builtin_amdgcn_mfma_f32_16x16x32_bf16(alf[mt], bhf, acc[mt][nt], 0, 0, 0); \
            acc[mt][nt] = __builtin_amdgcn_mfma_f32_16x16x32_bf16(ahf[mt], blf, acc[mt][nt], 0, 0, 0); \
        } \
    } \
}

    G2LOAD(0);
    G2WRITE();
    for (int k0 = 32; k0 < K; k0 += 32) {
        G2LOAD(k0);
        __syncthreads();
        G2COMP();
        __syncthreads();
        G2WRITE();
    }
    __syncthreads();
    G2COMP();
#undef G2LOAD
#undef G2WRITE
#undef G2COMP

    float bv[4];
#pragma unroll
    for (int nt = 0; nt < 4; ++nt) bv[nt] = bias[bn + wn + nt * 16 + col];

#pragma unroll
    for (int mt = 0; mt < 4; ++mt)
#pragma unroll
        for (int r = 0; r < 4; ++r) {
            const int row = bm + wm + mt * 16 + q4 * 4 + r;
#pragma unroll
            for (int nt = 0; nt < 4; ++nt)
                C[(size_t)row * N + bn + wn + nt * 16 + col] = acc[mt][nt][r] + bv[nt];
        }
}

// ---------------------------------------------------------------------------
// MFMA flash attention — R15 data path + inter-block K-split x2 (blockIdx.z).
// Fixed-max softmax => partials combine by plain sums in a separate merge
// kernel (no atomics; each block writes its private partial region).
// Block: 256 thr (4 waves), 128 q-rows, 1024 keys = 16 chunks of 64.
// Grid (32,16,2) = 1024 blocks = 4096 waves = 4/SIMD, 4 indep blocks/CU.
// ---------------------------------------------------------------------------
__global__ __launch_bounds__(256) void attn_mfma_kernel(
    const unsigned short* __restrict__ qkv,
    float* __restrict__ Op0, float* __restrict__ Op1,
    float* __restrict__ l0, float* __restrict__ l1)
{
    __shared__ __align__(16) unsigned short Ks[64 * 64];   // [key][dim] swizzled
    __shared__ __align__(16) unsigned short Vt[64 * 64];   // [dim][key] swizzled

    const int tid  = threadIdx.x;
    const int wave = tid >> 6;           // 0..3
    const int lane = tid & 63;
    const int l31  = lane & 31;
    const int lh   = lane >> 5;

    const int bh = blockIdx.x;           // b*16 + h
    const int qt = blockIdx.y;           // 0..15 (128 q-rows per block)
    const int ks = blockIdx.z;           // 0..1 key half
    const int b = bh >> 4;
    const int h = bh & 15;
    const int qrow0 = b * SEQ + qt * 128 + wave * 32;
    const int krow0 = b * SEQ + ks * 1024;

    float* __restrict__ Op = ks ? Op1 : Op0;
    float* __restrict__ lb = ks ? l1 : l0;

    // ---- permlane32_swap semantic probe (wave-uniform flag) ----
    bool s1;
    {
        int ta = lane, tb = 4096 + lane;
        asm volatile("v_permlane32_swap_b32 %0, %1" : "+v"(ta), "+v"(tb));
        s1 = __all((lane < 32) ? (ta == lane) : (ta == 4096 + lane - 32));
    }

    // Q fragments (B-operand), pre-scaled by C2F in GEMM1
    short8v qf[4];
    {
        const unsigned short* qsrc = qkv + (size_t)(qrow0 + l31) * (3 * D_MODEL) + h * 64 + lh * 8;
#pragma unroll
        for (int s = 0; s < 4; ++s)
            qf[s] = *(const short8v*)(qsrc + s * 16);
    }

    // staging indices (256 threads; 64-key chunk)
    const int krow = tid >> 2;           // 0..63
    const int koff = (tid & 3) * 16;     // 0,16,32,48
    const int vk0  = (tid & 31) * 2;     // 2 keys
    const int vd0  = (tid >> 5) * 8;     // 8 dims

    // running chunk pointers (advance by 64 rows per chunk)
    const unsigned short* kp = qkv + (size_t)(krow0 + krow) * (3 * D_MODEL)
                               + D_MODEL + h * 64 + koff;
    const unsigned short* vp = qkv + (size_t)(krow0 + vk0) * (3 * D_MODEL)
                               + 2 * D_MODEL + h * 64 + vd0;
    const ptrdiff_t CSTRIDE = (ptrdiff_t)64 * 3 * D_MODEL;

    f32x16 ot0, ot1;
#pragma unroll
    for (int r = 0; r < 16; ++r) { ot0[r] = 0.f; ot1[r] = 0.f; }
    float ll = 0.f;

    short8v kg[2], vg[2];
    const int swr = (l31 & 7) << 3;

#define PLSWAP(a, b) asm volatile("v_permlane32_swap_b32 %0, %1" : "+v"(a), "+v"(b))

#define ALOAD() { \
    kg[0] = ((const short8v*)kp)[0]; \
    kg[1] = ((const short8v*)kp)[1]; \
    vg[0] = *(const short8v*)(vp); \
    vg[1] = *(const short8v*)(vp + 3 * D_MODEL); \
    kp += CSTRIDE; vp += CSTRIDE; \
}

#define AWRITE() { \
    const int base = krow * 64 + koff; \
    const int sw = (krow & 7) << 3; \
    *(short8v*)&Ks[(base)     ^ sw] = kg[0]; \
    *(short8v*)&Ks[(base + 8) ^ sw] = kg[1]; \
    _Pragma("unroll") \
    for (int j = 0; j < 8; ++j) { \
        ushort2 w; \
        w.x = ((const unsigned short*)&vg[0])[j]; \
        w.y = ((const unsigned short*)&vg[1])[j]; \
        const int d = vd0 + j; \
        *(ushort2*)&Vt[(d * 64 + vk0) ^ ((d & 7) << 3)] = w; \
    } \
}

#define ACOMPUTE() { \
    f32x16 st0, st1; \
    _Pragma("unroll") for (int r = 0; r < 16; ++r) { st0[r] = 0.f; st1[r] = 0.f; } \
    _Pragma("unroll") \
    for (int s = 0; s < 4; ++s) { \
        short8v kf0 = *(const short8v*)&Ks[(l31 * 64 + s * 16 + lh * 8) ^ swr]; \
        st0 = __builtin_amdgcn_mfma_f32_32x32x16_bf16(kf0, qf[s], st0, 0, 0, 0); \
    } \
    _Pragma("unroll") \
    for (int s = 0; s < 4; ++s) { \
        short8v kf1 = *(const short8v*)&Ks[((32 + l31) * 64 + s * 16 + lh * 8) ^ swr]; \
        st1 = __builtin_amdgcn_mfma_f32_32x32x16_bf16(kf1, qf[s], st1, 0, 0, 0); \
    } \
    _Pragma("unroll") \
    for (int r = 0; r < 16; ++r) { \
        st0[r] = __builtin_exp2f(st0[r]); \
        st1[r] = __builtin_exp2f(st1[r]); \
    } \
    { \
        float a0 = (st0[0] + st0[1]) + (st0[2] + st0[3]); \
        float a1 = (st0[4] + st0[5]) + (st0[6] + st0[7]); \
        float a2 = (st0[8] + st0[9]) + (st0[10] + st0[11]); \
        float a3 = (st0[12] + st0[13]) + (st0[14] + st0[15]); \
        float b0 = (st1[0] + st1[1]) + (st1[2] + st1[3]); \
        float b1 = (st1[4] + st1[5]) + (st1[6] + st1[7]); \
        float b2 = (st1[8] + st1[9]) + (st1[10] + st1[11]); \
        float b3 = (st1[12] + st1[13]) + (st1[14] + st1[15]); \
        float rs = ((a0 + a1) + (a2 + a3)) + ((b0 + b1) + (b2 + b3)); \
        rs += __shfl_xor(rs, 32); \
        ll += rs; \
    } \
    unsigned int pk[16]; \
    _Pragma("unroll") \
    for (int i2 = 0; i2 < 8; ++i2) { \
        pk[i2]     = cvtpk(st0[2 * i2], st0[2 * i2 + 1]); \
        pk[8 + i2] = cvtpk(st1[2 * i2], st1[2 * i2 + 1]); \
    } \
    if (s1) { \
        PLSWAP(pk[0], pk[2]);   PLSWAP(pk[1], pk[3]); \
        PLSWAP(pk[4], pk[6]);   PLSWAP(pk[5], pk[7]); \
        PLSWAP(pk[8], pk[10]);  PLSWAP(pk[9], pk[11]); \
        PLSWAP(pk[12], pk[14]); PLSWAP(pk[13], pk[15]); \
    } else { \
        PLSWAP(pk[2], pk[0]);   PLSWAP(pk[3], pk[1]); \
        PLSWAP(pk[6], pk[4]);   PLSWAP(pk[7], pk[5]); \
        PLSWAP(pk[10], pk[8]);  PLSWAP(pk[11], pk[9]); \
        PLSWAP(pk[14], pk[12]); PLSWAP(pk[15], pk[13]); \
    } \
    u32x4 pf[4]; \
    pf[0].x = pk[0];  pf[0].y = pk[1];  pf[0].z = pk[2];  pf[0].w = pk[3]; \
    pf[1].x = pk[4];  pf[1].y = pk[5];  pf[1].z = pk[6];  pf[1].w = pk[7]; \
    pf[2].x = pk[8];  pf[2].y = pk[9];  pf[2].z = pk[10]; pf[2].w = pk[11]; \
    pf[3].x = pk[12]; pf[3].y = pk[13]; pf[3].z = pk[14]; pf[3].w = pk[15]; \
    _Pragma("unroll") \
    for (int ks2 = 0; ks2 < 4; ++ks2) { \
        const short8v pfr = u2s(pf[ks2]); \
        const int keyoff = ks2 * 16 + lh * 8; \
        short8v vf0 = *(const short8v*)&Vt[(l31 * 64 + keyoff) ^ swr]; \
        ot0 = __builtin_amdgcn_mfma_f32_32x32x16_bf16(vf0, pfr, ot0, 0, 0, 0); \
        short8v vf1 = *(const short8v*)&Vt[((32 + l31) * 64 + keyoff) ^ swr]; \
        ot1 = __builtin_amdgcn_mfma_f32_32x32x16_bf16(vf1, pfr, ot1, 0, 0, 0); \
    } \
}

    // ---- software pipeline (R12 schedule), 16 chunks of 64 keys ----
    ALOAD();                     // chunk 0
    AWRITE();
    for (int i = 0; i < 15; ++i) {
        ALOAD();                 // chunk i+1, in flight during compute of i
        __syncthreads();         // writes of chunk i visible
        ACOMPUTE();              // chunk i
        __syncthreads();         // all reads of chunk i done
        AWRITE();                // chunk i+1 (loads landed during compute)
    }
    __syncthreads();
    ACOMPUTE();                  // chunk 15
#undef ALOAD
#undef AWRITE
#undef ACOMPUTE
#undef PLSWAP

    // ---- write fp32 partials (unnormalized) + l ----
    const int qrow = qrow0 + l31;
    float* dst = Op + (size_t)qrow * D_MODEL + h * 64;
#pragma unroll
    for (int r = 0; r < 16; ++r) {
        const int dloc = (r & 3) + 8 * (r >> 2) + 4 * lh;
        dst[dloc]      = ot0[r];
        dst[32 + dloc] = ot1[r];
    }
    if (lh == 0) lb[qrow * N_HEADS + h] = ll;
}

// ---------------------------------------------------------------------------
// Merge: aoh/aol = split_bf((Op0 + Op1) / (l0 + l1)).
// ---------------------------------------------------------------------------
__global__ __launch_bounds__(256) void merge_kernel(
    const float* __restrict__ Op0, const float* __restrict__ Op1,
    const float* __restrict__ l0, const float* __restrict__ l1,
    unsigned short* __restrict__ aoh, unsigned short* __restrict__ aol)
{
    const size_t e0 = ((size_t)blockIdx.x * 256 + threadIdx.x) * 8;
    const int row = (int)(e0 >> 10);
    const int col = (int)(e0 & 1023);
    const int hh  = col >> 6;
    const float il = 1.0f / (l0[row * N_HEADS + hh] + l1[row * N_HEADS + hh]);

    float4 a0 = *(const float4*)(Op0 + e0);
    float4 a1 = *(const float4*)(Op0 + e0 + 4);
    float4 b0 = *(const float4*)(Op1 + e0);
    float4 b1 = *(const float4*)(Op1 + e0 + 4);

    ushort4 ha, la, hb, lb;
    unsigned short hi, lo;
    split_bf((a0.x + b0.x) * il, hi, lo); ha.x = hi; la.x = lo;
    split_bf((a0.y + b0.y) * il, hi, lo); ha.y = hi; la.y = lo;
    split_bf((a0.z + b0.z) * il, hi, lo); ha.z = hi; la.z = lo;
    split_bf((a0.w + b0.w) * il, hi, lo); ha.w = hi; la.w = lo;
    split_bf((a1.x + b1.x) * il, hi, lo); hb.x = hi; lb.x = lo;
    split_bf((a1.y + b1.y) * il, hi, lo); hb.y = hi; lb.y = lo;
    split_bf((a1.z + b1.z) * il, hi, lo); hb.z = hi; lb.z = lo;
    split_bf((a1.w + b1.w) * il, hi, lo); hb.w = hi; lb.w = lo;

    *(ushort4*)(aoh + e0)     = ha;
    *(ushort4*)(aoh + e0 + 4) = hb;
    *(ushort4*)(aol + e0)     = la;
    *(ushort4*)(aol + e0 + 4) = lb;
}

// ---------------------------------------------------------------------------
extern "C" void kernel_launch(void* const* d_in, const int* in_sizes, int n_in,
                              void* d_out, int out_size, void* d_ws, size_t ws_size,
                              hipStream_t stream) {
    (void)in_sizes; (void)n_in; (void)out_size; (void)ws_size;

    const float* x     = (const float*)d_in[0];
    const float* w_qkv = (const float*)d_in[1];
    const float* b_qkv = (const float*)d_in[2];
    const float* w_out = (const float*)d_in[3];
    const float* b_out = (const float*)d_in[4];
    float* out = (float*)d_out;

    // ws layout with verified-disjoint overlays:
    //  [0,25.2M)       qkv_bf (bf16)        -- dead after attn
    //  [0,8.4M)        aoh  (overlay; written by merge, after qkv dead)
    //  [8.4M,16.8M)    aol  (overlay)
    //  [25.2M,42M)     Op0 fp32             -- written by attn
    //  [25.2M,31.5M)   wqkvT_h (overlay; dead after GEMM1, before attn writes)
    //  [42M,58.7M)     Op1 fp32
    //  [58.7M,59.0M)   l0   [59.0M,59.2M) l1
    //  [59.2M,61.3M)   woutT_h   [61.3M,63.4M) woutT_l
    char* ws = (char*)d_ws;
    unsigned short* qkv_bf  = (unsigned short*)(ws);
    unsigned short* aoh     = (unsigned short*)(ws);
    unsigned short* aol     = (unsigned short*)(ws + 8388608);
    float*          Op0     = (float*)(ws + 25165824);
    unsigned short* wqkvT_h = (unsigned short*)(ws + 25165824);
    float*          Op1     = (float*)(ws + 41943040);
    float*          l0      = (float*)(ws + 58720256);
    float*          l1      = (float*)(ws + 58982400);
    unsigned short* woutT_h = (unsigned short*)(ws + 59244544);
    unsigned short* woutT_l = (unsigned short*)(ws + 61341696);
    // end: 63,438,848 B

    // 1) weight prep
    splitT_kernel<<<dim3((D_MODEL / 64) * (3 * D_MODEL / 64)), 256, 0, stream>>>(
        w_qkv, wqkvT_h, (unsigned short*)nullptr, D_MODEL, 3 * D_MODEL, D_MODEL, 0);
    splitT_kernel<<<dim3((D_MODEL / 64) * (D_MODEL / 64)), 256, 0, stream>>>(
        w_out, woutT_h, woutT_l, D_MODEL, D_MODEL, 0, 1);

    // 2) QKV projection (1-term bf16)
    gemm_xw_kernel<<<dim3((NROWS / 128) * (3 * D_MODEL / 128)), 256, 0, stream>>>(
        x, wqkvT_h, b_qkv, qkv_bf, NROWS, 3 * D_MODEL, D_MODEL, D_MODEL);

    // 3) flash attention, inter-block K-split x2 (private partials, no atomics)
    attn_mfma_kernel<<<dim3(NBATCH * N_HEADS, SEQ / 128, 2), 256, 0, stream>>>(
        qkv_bf, Op0, Op1, l0, l1);

    // 4) merge partials -> hi/lo split
    merge_kernel<<<dim3(NROWS * D_MODEL / (256 * 8)), 256, 0, stream>>>(
        Op0, Op1, l0, l1, aoh, aol);

    // 5) output projection (3-term)
    gemm_ao_kernel<<<dim3((NROWS / 128) * (D_MODEL / 128)), 256, 0, stream>>>(
        aoh, aol, woutT_h, woutT_l, b_out, out, NROWS, D_MODEL, D_MODEL);
}

// Round 18
// 158.130 us; speedup vs baseline: 1.0261x; 1.0261x over previous
//
#include <hip/hip_runtime.h>
#include <hip/hip_bf16.h>
#include <math.h>

#define D_MODEL 1024
#define N_HEADS 16
#define D_HEAD  64
#define SEQ     2048
#define NBATCH  2
#define NROWS   (NBATCH * SEQ)      // 4096

#define C2F 0.18033688011112042f    // 0.125 * log2(e), folded into Q weights/bias

typedef __attribute__((ext_vector_type(8))) short short8v;        // 8 bf16
typedef __attribute__((ext_vector_type(4))) float f32x4;
typedef __attribute__((ext_vector_type(16))) float f32x16;
typedef __attribute__((ext_vector_type(4))) unsigned int u32x4;

__device__ __forceinline__ unsigned short f2bf(float x) {
    unsigned int u = __float_as_uint(x);
    return (unsigned short)((u + 0x7FFFu + ((u >> 16) & 1u)) >> 16);   // RNE
}
// truncation split: hi = top-16-bits of fp32, lo = RNE(x - hi)
__device__ __forceinline__ void split_bf(float x, unsigned short& hi, unsigned short& lo) {
    unsigned int u = __float_as_uint(x);
    unsigned int ht = u & 0xFFFF0000u;
    hi = (unsigned short)(ht >> 16);
    lo = f2bf(x - __uint_as_float(ht));
}
// packed RNE f32x2 -> bf16x2
__device__ __forceinline__ unsigned int cvtpk(float lo, float hi) {
    unsigned int r;
    asm("v_cvt_pk_bf16_f32 %0, %1, %2" : "=v"(r) : "v"(lo), "v"(hi));
    return r;
}
__device__ __forceinline__ short8v u2s(u32x4 v) {
    union { u32x4 u; short8v s; } c; c.u = v; return c.s;
}

// ---------------------------------------------------------------------------
// Fused weight prep (one launch). Blocks [0, nq) handle w_qkv -> RNE bf16
// (Q cols pre-scaled by C2F); blocks [nq, nq+no) handle w_out -> hi/lo split.
// ---------------------------------------------------------------------------
__global__ __launch_bounds__(256) void weightprep_kernel(
    const float* __restrict__ Wq, unsigned short* __restrict__ Tq,
    const float* __restrict__ Wo, unsigned short* __restrict__ Toh,
    unsigned short* __restrict__ Tol, int nq)
{
    __shared__ float tile[64][68];
    const int tid = threadIdx.x;
    const bool isQ = ((int)blockIdx.x < nq);
    const int bid = isQ ? blockIdx.x : (blockIdx.x - nq);
    const int N = isQ ? (3 * D_MODEL) : D_MODEL;
    const int K = D_MODEL;
    const float* W = isQ ? Wq : Wo;
    const int nbn = N >> 6;
    const int k0 = (bid / nbn) << 6;
    const int n0 = (bid % nbn) << 6;
    const int r  = tid >> 4;
    const int c4 = (tid & 15) * 4;

#pragma unroll
    for (int i = 0; i < 4; ++i) {
        float4 v = *(const float4*)(W + (size_t)(k0 + r + i * 16) * N + n0 + c4);
        *(float4*)&tile[r + i * 16][c4] = v;
    }
    __syncthreads();

    const int kl = (tid & 15) * 4;
#pragma unroll
    for (int i = 0; i < 4; ++i) {
        const int nl = (tid >> 4) + i * 16;
        if (isQ) {
            const float sc = (n0 + nl < D_MODEL) ? C2F : 1.0f;
            ushort4 h4;
            h4.x = f2bf(tile[kl + 0][nl] * sc);
            h4.y = f2bf(tile[kl + 1][nl] * sc);
            h4.z = f2bf(tile[kl + 2][nl] * sc);
            h4.w = f2bf(tile[kl + 3][nl] * sc);
            *(ushort4*)(Tq + (size_t)(n0 + nl) * K + k0 + kl) = h4;
        } else {
            ushort4 h4, l4;
            unsigned short h, l;
            split_bf(tile[kl + 0][nl], h, l); h4.x = h; l4.x = l;
            split_bf(tile[kl + 1][nl], h, l); h4.y = h; l4.y = l;
            split_bf(tile[kl + 2][nl], h, l); h4.z = h; l4.z = l;
            split_bf(tile[kl + 3][nl], h, l); h4.w = h; l4.w = l;
            *(ushort4*)(Toh + (size_t)(n0 + nl) * K + k0 + kl) = h4;
            *(ushort4*)(Tol + (size_t)(n0 + nl) * K + k0 + kl) = l4;
        }
    }
}

// ---------------------------------------------------------------------------
// GEMM1 (1-term bf16): qkv[M,N](bf16) = RNE_bf16(A) @ Bh[N,K]^T + bias.
// ---------------------------------------------------------------------------
#define ASTRIDE 40    // bf16 elems; 80B row stride

__global__ __launch_bounds__(256) void gemm_xw_kernel(
    const float* __restrict__ A,
    const unsigned short* __restrict__ Bth,
    const float* __restrict__ bias,
    unsigned short* __restrict__ C, int M, int N, int K, int qcols)
{
    __shared__ __align__(16) unsigned short Ab[128][ASTRIDE];
    __shared__ __align__(16) unsigned short Bh[128][ASTRIDE];

    const int tid  = threadIdx.x;
    const int wave = tid >> 6;
    const int lane = tid & 63;
    const int col  = lane & 15;
    const int q4   = lane >> 4;
    const int wm   = (wave >> 1) * 64;
    const int wn   = (wave & 1) * 64;

    const int nwg = gridDim.x;
    const int cpx = nwg >> 3;
    const int swz = (blockIdx.x & 7) * cpx + (blockIdx.x >> 3);
    const int nbn = N / 128;
    const int bm = (swz / nbn) * 128;
    const int bn = (swz % nbn) * 128;

    const int sr = tid >> 1;
    const int sq = (tid & 1) * 16;
    const float* aptr = A + (size_t)(bm + sr) * K + sq;
    const unsigned short* bhp = Bth + (size_t)(bn + sr) * K + sq;

    f32x4 acc[4][4];
#pragma unroll
    for (int i = 0; i < 4; ++i)
#pragma unroll
        for (int j = 0; j < 4; ++j) acc[i][j] = (f32x4){0.f, 0.f, 0.f, 0.f};

    float4 a0, a1, a2, a3;
    short8v b0h, b1h;

#define G1LOAD(k0) { \
    a0 = *(const float4*)(aptr + (k0)); \
    a1 = *(const float4*)(aptr + (k0) + 4); \
    a2 = *(const float4*)(aptr + (k0) + 8); \
    a3 = *(const float4*)(aptr + (k0) + 12); \
    b0h = *(const short8v*)(bhp + (k0)); \
    b1h = *(const short8v*)(bhp + (k0) + 8); \
}

#define G1WRITE() { \
    u32x4 p0, p1; \
    p0.x = cvtpk(a0.x, a0.y); p0.y = cvtpk(a0.z, a0.w); \
    p0.z = cvtpk(a1.x, a1.y); p0.w = cvtpk(a1.z, a1.w); \
    p1.x = cvtpk(a2.x, a2.y); p1.y = cvtpk(a2.z, a2.w); \
    p1.z = cvtpk(a3.x, a3.y); p1.w = cvtpk(a3.z, a3.w); \
    *(u32x4*)&Ab[sr][sq]     = p0; \
    *(u32x4*)&Ab[sr][sq + 8] = p1; \
    *(short8v*)&Bh[sr][sq]     = b0h; \
    *(short8v*)&Bh[sr][sq + 8] = b1h; \
}

#define G1COMP() { \
    short8v af[4]; \
    _Pragma("unroll") \
    for (int mt = 0; mt < 4; ++mt) \
        af[mt] = *(const short8v*)&Ab[wm + mt * 16 + col][q4 * 8]; \
    _Pragma("unroll") \
    for (int nt = 0; nt < 4; ++nt) { \
        short8v bhf = *(const short8v*)&Bh[wn + nt * 16 + col][q4 * 8]; \
        _Pragma("unroll") \
        for (int mt = 0; mt < 4; ++mt) \
            acc[mt][nt] = __builtin_amdgcn_mfma_f32_16x16x32_bf16(af[mt], bhf, acc[mt][nt], 0, 0, 0); \
    } \
}

    G1LOAD(0);
    G1WRITE();
    for (int k0 = 32; k0 < K; k0 += 32) {
        G1LOAD(k0);
        __syncthreads();
        G1COMP();
        __syncthreads();
        G1WRITE();
    }
    __syncthreads();
    G1COMP();
#undef G1LOAD
#undef G1WRITE
#undef G1COMP

    const float bscale = (bn < qcols) ? C2F : 1.0f;
    float bv[4];
#pragma unroll
    for (int nt = 0; nt < 4; ++nt) bv[nt] = bias[bn + wn + nt * 16 + col] * bscale;

#pragma unroll
    for (int mt = 0; mt < 4; ++mt)
#pragma unroll
        for (int r = 0; r < 4; ++r) {
            const int row = bm + wm + mt * 16 + q4 * 4 + r;
#pragma unroll
            for (int nt = 0; nt < 4; ++nt)
                C[(size_t)row * N + bn + wn + nt * 16 + col] = f2bf(acc[mt][nt][r] + bv[nt]);
        }
}

// ---------------------------------------------------------------------------
// GEMM2: out[M,N](fp32) = (Aoh+Aol)[M,K] @ (Bh+Bl)[N,K]^T + bias, 3-term.
// ---------------------------------------------------------------------------
__global__ __launch_bounds__(256) void gemm_ao_kernel(
    const unsigned short* __restrict__ Aoh,
    const unsigned short* __restrict__ Aol,
    const unsigned short* __restrict__ Bth,
    const unsigned short* __restrict__ Btl,
    const float* __restrict__ bias,
    float* __restrict__ C, int M, int N, int K)
{
    __shared__ __align__(16) unsigned short Ah[128][ASTRIDE];
    __shared__ __align__(16) unsigned short Al[128][ASTRIDE];
    __shared__ __align__(16) unsigned short Bh[128][ASTRIDE];
    __shared__ __align__(16) unsigned short Bl[128][ASTRIDE];

    const int tid  = threadIdx.x;
    const int wave = tid >> 6;
    const int lane = tid & 63;
    const int col  = lane & 15;
    const int q4   = lane >> 4;
    const int wm   = (wave >> 1) * 64;
    const int wn   = (wave & 1) * 64;

    const int nwg = gridDim.x;
    const int cpx = nwg >> 3;
    const int swz = (blockIdx.x & 7) * cpx + (blockIdx.x >> 3);
    const int nbn = N / 128;
    const int bm = (swz / nbn) * 128;
    const int bn = (swz % nbn) * 128;

    const int sr = tid >> 1;
    const int sq = (tid & 1) * 16;
    const unsigned short* ahp = Aoh + (size_t)(bm + sr) * K + sq;
    const unsigned short* alp = Aol + (size_t)(bm + sr) * K + sq;
    const unsigned short* bhp = Bth + (size_t)(bn + sr) * K + sq;
    const unsigned short* blp = Btl + (size_t)(bn + sr) * K + sq;

    f32x4 acc[4][4];
#pragma unroll
    for (int i = 0; i < 4; ++i)
#pragma unroll
        for (int j = 0; j < 4; ++j) acc[i][j] = (f32x4){0.f, 0.f, 0.f, 0.f};

    short8v a0h, a1h, a0l, a1l, b0h, b1h, b0l, b1l;

#define G2LOAD(k0) { \
    a0h = *(const short8v*)(ahp + (k0)); \
    a1h = *(const short8v*)(ahp + (k0) + 8); \
    a0l = *(const short8v*)(alp + (k0)); \
    a1l = *(const short8v*)(alp + (k0) + 8); \
    b0h = *(const short8v*)(bhp + (k0)); \
    b1h = *(const short8v*)(bhp + (k0) + 8); \
    b0l = *(const short8v*)(blp + (k0)); \
    b1l = *(const short8v*)(blp + (k0) + 8); \
}

#define G2WRITE() { \
    *(short8v*)&Ah[sr][sq]     = a0h; \
    *(short8v*)&Ah[sr][sq + 8] = a1h; \
    *(short8v*)&Al[sr][sq]     = a0l; \
    *(short8v*)&Al[sr][sq + 8] = a1l; \
    *(short8v*)&Bh[sr][sq]     = b0h; \
    *(short8v*)&Bh[sr][sq + 8] = b1h; \
    *(short8v*)&Bl[sr][sq]     = b0l; \
    *(short8v*)&Bl[sr][sq + 8] = b1l; \
}

#define G2COMP() { \
    short8v ahf[4], alf[4]; \
    _Pragma("unroll") \
    for (int mt = 0; mt < 4; ++mt) { \
        ahf[mt] = *(const short8v*)&Ah[wm + mt * 16 + col][q4 * 8]; \
        alf[mt] = *(const short8v*)&Al[wm + mt * 16 + col][q4 * 8]; \
    } \
    _Pragma("unroll") \
    for (int nt = 0; nt < 4; ++nt) { \
        short8v bhf = *(const short8v*)&Bh[wn + nt * 16 + col][q4 * 8]; \
        short8v blf = *(const short8v*)&Bl[wn + nt * 16 + col][q4 * 8]; \
        _Pragma("unroll") \
        for (int mt = 0; mt < 4; ++mt) { \
            acc[mt][nt] = __builtin_amdgcn_mfma_f32_16x16x32_bf16(ahf[mt], bhf, acc[mt][nt], 0, 0, 0); \
            acc[mt][nt] = __builtin_amdgcn_mfma_f32_16x16x32_bf16(alf[mt], bhf, acc[mt][nt], 0, 0, 0); \
            acc[mt][nt] = __builtin_amdgcn_mfma_f32_16x16x32_bf16(ahf[mt], blf, acc[mt][nt], 0, 0, 0); \
        } \
    } \
}

    G2LOAD(0);
    G2WRITE();
    for (int k0 = 32; k0 < K; k0 += 32) {
        G2LOAD(k0);
        __syncthreads();
        G2COMP();
        __syncthreads();
        G2WRITE();
    }
    __syncthreads();
    G2COMP();
#undef G2LOAD
#undef G2WRITE
#undef G2COMP

    float bv[4];
#pragma unroll
    for (int nt = 0; nt < 4; ++nt) bv[nt] = bias[bn + wn + nt * 16 + col];

#pragma unroll
    for (int mt = 0; mt < 4; ++mt)
#pragma unroll
        for (int r = 0; r < 4; ++r) {
            const int row = bm + wm + mt * 16 + q4 * 4 + r;
#pragma unroll
            for (int nt = 0; nt < 4; ++nt)
                C[(size_t)row * N + bn + wn + nt * 16 + col] = acc[mt][nt][r] + bv[nt];
        }
}

// ---------------------------------------------------------------------------
// MFMA flash attention — exact R15 structure (best measured: 72 µs) with
// s_setprio(1) wrapped around the MFMA clusters (T5; additive, no layout
// or schedule change). 256-thread blocks, 128 q-rows, KBLK=64.
// ---------------------------------------------------------------------------
__global__ __launch_bounds__(256) void attn_mfma_kernel(
    const unsigned short* __restrict__ qkv,
    unsigned short* __restrict__ aoh, unsigned short* __restrict__ aol)
{
    __shared__ __align__(16) unsigned short Ks[64 * 64];   // [key][dim] swizzled
    __shared__ __align__(16) unsigned short Vt[64 * 64];   // [dim][key] swizzled

    const int tid  = threadIdx.x;
    const int wave = tid >> 6;           // 0..3
    const int lane = tid & 63;
    const int l31  = lane & 31;
    const int lh   = lane >> 5;

    const int bh = blockIdx.x;           // b*16 + h
    const int qt = blockIdx.y;           // 0..15 (128 q-rows per block)
    const int b = bh >> 4;
    const int h = bh & 15;
    const int qrow0 = b * SEQ + qt * 128 + wave * 32;
    const int krow0 = b * SEQ;

    // ---- permlane32_swap semantic probe (wave-uniform flag) ----
    bool s1;
    {
        int ta = lane, tb = 4096 + lane;
        asm volatile("v_permlane32_swap_b32 %0, %1" : "+v"(ta), "+v"(tb));
        s1 = __all((lane < 32) ? (ta == lane) : (ta == 4096 + lane - 32));
    }

    // Q fragments (B-operand), pre-scaled by C2F in GEMM1
    short8v qf[4];
    {
        const unsigned short* qsrc = qkv + (size_t)(qrow0 + l31) * (3 * D_MODEL) + h * 64 + lh * 8;
#pragma unroll
        for (int s = 0; s < 4; ++s)
            qf[s] = *(const short8v*)(qsrc + s * 16);
    }

    // staging indices (256 threads; per-thread work halved vs 128-thread)
    const int krow = tid >> 2;           // 0..63
    const int koff = (tid & 3) * 16;     // 0,16,32,48
    const int vk0  = (tid & 31) * 2;     // 2 keys
    const int vd0  = (tid >> 5) * 8;     // 8 dims

    // running chunk pointers (advance by 64 rows per chunk)
    const unsigned short* kp = qkv + (size_t)(krow0 + krow) * (3 * D_MODEL)
                               + D_MODEL + h * 64 + koff;
    const unsigned short* vp = qkv + (size_t)(krow0 + vk0) * (3 * D_MODEL)
                               + 2 * D_MODEL + h * 64 + vd0;
    const ptrdiff_t CSTRIDE = (ptrdiff_t)64 * 3 * D_MODEL;

    f32x16 ot0, ot1;
#pragma unroll
    for (int r = 0; r < 16; ++r) { ot0[r] = 0.f; ot1[r] = 0.f; }
    float ll = 0.f;

    short8v kg[2], vg[2];
    const int swr = (l31 & 7) << 3;

#define PLSWAP(a, b) asm volatile("v_permlane32_swap_b32 %0, %1" : "+v"(a), "+v"(b))

#define ALOAD() { \
    kg[0] = ((const short8v*)kp)[0]; \
    kg[1] = ((const short8v*)kp)[1]; \
    vg[0] = *(const short8v*)(vp); \
    vg[1] = *(const short8v*)(vp + 3 * D_MODEL); \
    kp += CSTRIDE; vp += CSTRIDE; \
}

#define AWRITE() { \
    const int base = krow * 64 + koff; \
    const int sw = (krow & 7) << 3; \
    *(short8v*)&Ks[(base)     ^ sw] = kg[0]; \
    *(short8v*)&Ks[(base + 8) ^ sw] = kg[1]; \
    _Pragma("unroll") \
    for (int j = 0; j < 8; ++j) { \
        ushort2 w; \
        w.x = ((const unsigned short*)&vg[0])[j]; \
        w.y = ((const unsigned short*)&vg[1])[j]; \
        const int d = vd0 + j; \
        *(ushort2*)&Vt[(d * 64 + vk0) ^ ((d & 7) << 3)] = w; \
    } \
}

#define ACOMPUTE() { \
    f32x16 st0, st1; \
    _Pragma("unroll") for (int r = 0; r < 16; ++r) { st0[r] = 0.f; st1[r] = 0.f; } \
    __builtin_amdgcn_s_setprio(1); \
    _Pragma("unroll") \
    for (int s = 0; s < 4; ++s) { \
        short8v kf0 = *(const short8v*)&Ks[(l31 * 64 + s * 16 + lh * 8) ^ swr]; \
        st0 = __builtin_amdgcn_mfma_f32_32x32x16_bf16(kf0, qf[s], st0, 0, 0, 0); \
    } \
    _Pragma("unroll") \
    for (int s = 0; s < 4; ++s) { \
        short8v kf1 = *(const short8v*)&Ks[((32 + l31) * 64 + s * 16 + lh * 8) ^ swr]; \
        st1 = __builtin_amdgcn_mfma_f32_32x32x16_bf16(kf1, qf[s], st1, 0, 0, 0); \
    } \
    __builtin_amdgcn_s_setprio(0); \
    _Pragma("unroll") \
    for (int r = 0; r < 16; ++r) { \
        st0[r] = __builtin_exp2f(st0[r]); \
        st1[r] = __builtin_exp2f(st1[r]); \
    } \
    { \
        float a0 = (st0[0] + st0[1]) + (st0[2] + st0[3]); \
        float a1 = (st0[4] + st0[5]) + (st0[6] + st0[7]); \
        float a2 = (st0[8] + st0[9]) + (st0[10] + st0[11]); \
        float a3 = (st0[12] + st0[13]) + (st0[14] + st0[15]); \
        float b0 = (st1[0] + st1[1]) + (st1[2] + st1[3]); \
        float b1 = (st1[4] + st1[5]) + (st1[6] + st1[7]); \
        float b2 = (st1[8] + st1[9]) + (st1[10] + st1[11]); \
        float b3 = (st1[12] + st1[13]) + (st1[14] + st1[15]); \
        float rs = ((a0 + a1) + (a2 + a3)) + ((b0 + b1) + (b2 + b3)); \
        rs += __shfl_xor(rs, 32); \
        ll += rs; \
    } \
    unsigned int pk[16]; \
    _Pragma("unroll") \
    for (int i2 = 0; i2 < 8; ++i2) { \
        pk[i2]     = cvtpk(st0[2 * i2], st0[2 * i2 + 1]); \
        pk[8 + i2] = cvtpk(st1[2 * i2], st1[2 * i2 + 1]); \
    } \
    if (s1) { \
        PLSWAP(pk[0], pk[2]);   PLSWAP(pk[1], pk[3]); \
        PLSWAP(pk[4], pk[6]);   PLSWAP(pk[5], pk[7]); \
        PLSWAP(pk[8], pk[10]);  PLSWAP(pk[9], pk[11]); \
        PLSWAP(pk[12], pk[14]); PLSWAP(pk[13], pk[15]); \
    } else { \
        PLSWAP(pk[2], pk[0]);   PLSWAP(pk[3], pk[1]); \
        PLSWAP(pk[6], pk[4]);   PLSWAP(pk[7], pk[5]); \
        PLSWAP(pk[10], pk[8]);  PLSWAP(pk[11], pk[9]); \
        PLSWAP(pk[14], pk[12]); PLSWAP(pk[15], pk[13]); \
    } \
    u32x4 pf[4]; \
    pf[0].x = pk[0];  pf[0].y = pk[1];  pf[0].z = pk[2];  pf[0].w = pk[3]; \
    pf[1].x = pk[4];  pf[1].y = pk[5];  pf[1].z = pk[6];  pf[1].w = pk[7]; \
    pf[2].x = pk[8];  pf[2].y = pk[9];  pf[2].z = pk[10]; pf[2].w = pk[11]; \
    pf[3].x = pk[12]; pf[3].y = pk[13]; pf[3].z = pk[14]; pf[3].w = pk[15]; \
    __builtin_amdgcn_s_setprio(1); \
    _Pragma("unroll") \
    for (int ks2 = 0; ks2 < 4; ++ks2) { \
        const short8v pfr = u2s(pf[ks2]); \
        const int keyoff = ks2 * 16 + lh * 8; \
        short8v vf0 = *(const short8v*)&Vt[(l31 * 64 + keyoff) ^ swr]; \
        ot0 = __builtin_amdgcn_mfma_f32_32x32x16_bf16(vf0, pfr, ot0, 0, 0, 0); \
        short8v vf1 = *(const short8v*)&Vt[((32 + l31) * 64 + keyoff) ^ swr]; \
        ot1 = __builtin_amdgcn_mfma_f32_32x32x16_bf16(vf1, pfr, ot1, 0, 0, 0); \
    } \
    __builtin_amdgcn_s_setprio(0); \
}

    // ---- software pipeline (R12 schedule) ----
    ALOAD();                     // chunk 0
    AWRITE();
    for (int i = 0; i < 31; ++i) {
        ALOAD();                 // chunk i+1, in flight during compute of i
        __syncthreads();         // writes of chunk i visible
        ACOMPUTE();              // chunk i
        __syncthreads();         // all reads of chunk i done
        AWRITE();                // chunk i+1 (loads landed during compute)
    }
    __syncthreads();
    ACOMPUTE();                  // chunk 31
#undef ALOAD
#undef AWRITE
#undef ACOMPUTE
#undef PLSWAP

    // ---- finalize: lane holds q = l31; O^T rows are dims ----
    const float il = 1.0f / ll;
    const int qrow = qrow0 + l31;
    unsigned short* dh = aoh + (size_t)qrow * D_MODEL + h * 64;
    unsigned short* dl = aol + (size_t)qrow * D_MODEL + h * 64;
#pragma unroll
    for (int r = 0; r < 16; ++r) {
        const int dloc = (r & 3) + 8 * (r >> 2) + 4 * lh;
        unsigned short hh, lo2;
        split_bf(ot0[r] * il, hh, lo2);
        dh[dloc] = hh; dl[dloc] = lo2;
        split_bf(ot1[r] * il, hh, lo2);
        dh[32 + dloc] = hh; dl[32 + dloc] = lo2;
    }
}

// ---------------------------------------------------------------------------
extern "C" void kernel_launch(void* const* d_in, const int* in_sizes, int n_in,
                              void* d_out, int out_size, void* d_ws, size_t ws_size,
                              hipStream_t stream) {
    (void)in_sizes; (void)n_in; (void)out_size; (void)ws_size;

    const float* x     = (const float*)d_in[0];
    const float* w_qkv = (const float*)d_in[1];
    const float* b_qkv = (const float*)d_in[2];
    const float* w_out = (const float*)d_in[3];
    const float* b_out = (const float*)d_in[4];
    float* out = (float*)d_out;

    char* ws = (char*)d_ws;
    unsigned short* qkv_bf  = (unsigned short*)(ws);                   // 25,165,824
    unsigned short* aoh     = (unsigned short*)(ws + 25165824);        //  8,388,608
    unsigned short* aol     = (unsigned short*)(ws + 33554432);        //  8,388,608
    unsigned short* wqkvT_h = (unsigned short*)(ws + 41943040);        //  6,291,456
    unsigned short* woutT_h = (unsigned short*)(ws + 48234496);        //  2,097,152
    unsigned short* woutT_l = (unsigned short*)(ws + 50331648);        //  2,097,152
    // end: 52,428,800 B

    // 1) fused weight prep (one launch): w_qkv RNE (Q cols scaled), w_out split
    {
        const int nq = (D_MODEL / 64) * (3 * D_MODEL / 64);   // 768
        const int no = (D_MODEL / 64) * (D_MODEL / 64);       // 256
        weightprep_kernel<<<dim3(nq + no), 256, 0, stream>>>(
            w_qkv, wqkvT_h, w_out, woutT_h, woutT_l, nq);
    }

    // 2) QKV projection (1-term bf16)
    gemm_xw_kernel<<<dim3((NROWS / 128) * (3 * D_MODEL / 128)), 256, 0, stream>>>(
        x, wqkvT_h, b_qkv, qkv_bf, NROWS, 3 * D_MODEL, D_MODEL, D_MODEL);

    // 3) flash attention (R15 structure + setprio)
    attn_mfma_kernel<<<dim3(NBATCH * N_HEADS, SEQ / 128), 256, 0, stream>>>(qkv_bf, aoh, aol);

    // 4) output projection (3-term)
    gemm_ao_kernel<<<dim3((NROWS / 128) * (D_MODEL / 128)), 256, 0, stream>>>(
        aoh, aol, woutT_h, woutT_l, b_out, out, NROWS, D_MODEL, D_MODEL);
}

// Round 19
// 153.196 us; speedup vs baseline: 1.0591x; 1.0322x over previous
//
#include <hip/hip_runtime.h>
#include <hip/hip_bf16.h>
#include <math.h>

#define D_MODEL 1024
#define N_HEADS 16
#define D_HEAD  64
#define SEQ     2048
#define NBATCH  2
#define NROWS   (NBATCH * SEQ)      // 4096

#define C2F 0.18033688011112042f    // 0.125 * log2(e), folded into Q weights/bias

typedef __attribute__((ext_vector_type(8))) short short8v;        // 8 bf16
typedef __attribute__((ext_vector_type(4))) float f32x4;
typedef __attribute__((ext_vector_type(16))) float f32x16;
typedef __attribute__((ext_vector_type(4))) unsigned int u32x4;

__device__ __forceinline__ unsigned short f2bf(float x) {
    unsigned int u = __float_as_uint(x);
    return (unsigned short)((u + 0x7FFFu + ((u >> 16) & 1u)) >> 16);   // RNE
}
// truncation split: hi = top-16-bits of fp32, lo = RNE(x - hi)
__device__ __forceinline__ void split_bf(float x, unsigned short& hi, unsigned short& lo) {
    unsigned int u = __float_as_uint(x);
    unsigned int ht = u & 0xFFFF0000u;
    hi = (unsigned short)(ht >> 16);
    lo = f2bf(x - __uint_as_float(ht));
}
// packed RNE f32x2 -> bf16x2
__device__ __forceinline__ unsigned int cvtpk(float lo, float hi) {
    unsigned int r;
    asm("v_cvt_pk_bf16_f32 %0, %1, %2" : "=v"(r) : "v"(lo), "v"(hi));
    return r;
}
__device__ __forceinline__ short8v u2s(u32x4 v) {
    union { u32x4 u; short8v s; } c; c.u = v; return c.s;
}

// ---------------------------------------------------------------------------
// Fused weight prep (one launch). Blocks [0, nq) handle w_qkv -> RNE bf16
// (Q cols pre-scaled by C2F); blocks [nq, nq+no) handle w_out -> hi/lo split.
// ---------------------------------------------------------------------------
__global__ __launch_bounds__(256) void weightprep_kernel(
    const float* __restrict__ Wq, unsigned short* __restrict__ Tq,
    const float* __restrict__ Wo, unsigned short* __restrict__ Toh,
    unsigned short* __restrict__ Tol, int nq)
{
    __shared__ float tile[64][68];
    const int tid = threadIdx.x;
    const bool isQ = ((int)blockIdx.x < nq);
    const int bid = isQ ? blockIdx.x : (blockIdx.x - nq);
    const int N = isQ ? (3 * D_MODEL) : D_MODEL;
    const int K = D_MODEL;
    const float* W = isQ ? Wq : Wo;
    const int nbn = N >> 6;
    const int k0 = (bid / nbn) << 6;
    const int n0 = (bid % nbn) << 6;
    const int r  = tid >> 4;
    const int c4 = (tid & 15) * 4;

#pragma unroll
    for (int i = 0; i < 4; ++i) {
        float4 v = *(const float4*)(W + (size_t)(k0 + r + i * 16) * N + n0 + c4);
        *(float4*)&tile[r + i * 16][c4] = v;
    }
    __syncthreads();

    const int kl = (tid & 15) * 4;
#pragma unroll
    for (int i = 0; i < 4; ++i) {
        const int nl = (tid >> 4) + i * 16;
        if (isQ) {
            const float sc = (n0 + nl < D_MODEL) ? C2F : 1.0f;
            ushort4 h4;
            h4.x = f2bf(tile[kl + 0][nl] * sc);
            h4.y = f2bf(tile[kl + 1][nl] * sc);
            h4.z = f2bf(tile[kl + 2][nl] * sc);
            h4.w = f2bf(tile[kl + 3][nl] * sc);
            *(ushort4*)(Tq + (size_t)(n0 + nl) * K + k0 + kl) = h4;
        } else {
            ushort4 h4, l4;
            unsigned short h, l;
            split_bf(tile[kl + 0][nl], h, l); h4.x = h; l4.x = l;
            split_bf(tile[kl + 1][nl], h, l); h4.y = h; l4.y = l;
            split_bf(tile[kl + 2][nl], h, l); h4.z = h; l4.z = l;
            split_bf(tile[kl + 3][nl], h, l); h4.w = h; l4.w = l;
            *(ushort4*)(Toh + (size_t)(n0 + nl) * K + k0 + kl) = h4;
            *(ushort4*)(Tol + (size_t)(n0 + nl) * K + k0 + kl) = l4;
        }
    }
}

// ---------------------------------------------------------------------------
// GEMM1 (1-term bf16): qkv[M,N](bf16) = RNE_bf16(A) @ Bh[N,K]^T + bias.
// ---------------------------------------------------------------------------
#define ASTRIDE 40    // bf16 elems; 80B row stride

__global__ __launch_bounds__(256) void gemm_xw_kernel(
    const float* __restrict__ A,
    const unsigned short* __restrict__ Bth,
    const float* __restrict__ bias,
    unsigned short* __restrict__ C, int M, int N, int K, int qcols)
{
    __shared__ __align__(16) unsigned short Ab[128][ASTRIDE];
    __shared__ __align__(16) unsigned short Bh[128][ASTRIDE];

    const int tid  = threadIdx.x;
    const int wave = tid >> 6;
    const int lane = tid & 63;
    const int col  = lane & 15;
    const int q4   = lane >> 4;
    const int wm   = (wave >> 1) * 64;
    const int wn   = (wave & 1) * 64;

    const int nwg = gridDim.x;
    const int cpx = nwg >> 3;
    const int swz = (blockIdx.x & 7) * cpx + (blockIdx.x >> 3);
    const int nbn = N / 128;
    const int bm = (swz / nbn) * 128;
    const int bn = (swz % nbn) * 128;

    const int sr = tid >> 1;
    const int sq = (tid & 1) * 16;
    const float* aptr = A + (size_t)(bm + sr) * K + sq;
    const unsigned short* bhp = Bth + (size_t)(bn + sr) * K + sq;

    f32x4 acc[4][4];
#pragma unroll
    for (int i = 0; i < 4; ++i)
#pragma unroll
        for (int j = 0; j < 4; ++j) acc[i][j] = (f32x4){0.f, 0.f, 0.f, 0.f};

    float4 a0, a1, a2, a3;
    short8v b0h, b1h;

#define G1LOAD(k0) { \
    a0 = *(const float4*)(aptr + (k0)); \
    a1 = *(const float4*)(aptr + (k0) + 4); \
    a2 = *(const float4*)(aptr + (k0) + 8); \
    a3 = *(const float4*)(aptr + (k0) + 12); \
    b0h = *(const short8v*)(bhp + (k0)); \
    b1h = *(const short8v*)(bhp + (k0) + 8); \
}

#define G1WRITE() { \
    u32x4 p0, p1; \
    p0.x = cvtpk(a0.x, a0.y); p0.y = cvtpk(a0.z, a0.w); \
    p0.z = cvtpk(a1.x, a1.y); p0.w = cvtpk(a1.z, a1.w); \
    p1.x = cvtpk(a2.x, a2.y); p1.y = cvtpk(a2.z, a2.w); \
    p1.z = cvtpk(a3.x, a3.y); p1.w = cvtpk(a3.z, a3.w); \
    *(u32x4*)&Ab[sr][sq]     = p0; \
    *(u32x4*)&Ab[sr][sq + 8] = p1; \
    *(short8v*)&Bh[sr][sq]     = b0h; \
    *(short8v*)&Bh[sr][sq + 8] = b1h; \
}

#define G1COMP() { \
    short8v af[4]; \
    _Pragma("unroll") \
    for (int mt = 0; mt < 4; ++mt) \
        af[mt] = *(const short8v*)&Ab[wm + mt * 16 + col][q4 * 8]; \
    _Pragma("unroll") \
    for (int nt = 0; nt < 4; ++nt) { \
        short8v bhf = *(const short8v*)&Bh[wn + nt * 16 + col][q4 * 8]; \
        _Pragma("unroll") \
        for (int mt = 0; mt < 4; ++mt) \
            acc[mt][nt] = __builtin_amdgcn_mfma_f32_16x16x32_bf16(af[mt], bhf, acc[mt][nt], 0, 0, 0); \
    } \
}

    G1LOAD(0);
    G1WRITE();
    for (int k0 = 32; k0 < K; k0 += 32) {
        G1LOAD(k0);
        __syncthreads();
        G1COMP();
        __syncthreads();
        G1WRITE();
    }
    __syncthreads();
    G1COMP();
#undef G1LOAD
#undef G1WRITE
#undef G1COMP

    const float bscale = (bn < qcols) ? C2F : 1.0f;
    float bv[4];
#pragma unroll
    for (int nt = 0; nt < 4; ++nt) bv[nt] = bias[bn + wn + nt * 16 + col] * bscale;

#pragma unroll
    for (int mt = 0; mt < 4; ++mt)
#pragma unroll
        for (int r = 0; r < 4; ++r) {
            const int row = bm + wm + mt * 16 + q4 * 4 + r;
#pragma unroll
            for (int nt = 0; nt < 4; ++nt)
                C[(size_t)row * N + bn + wn + nt * 16 + col] = f2bf(acc[mt][nt][r] + bv[nt]);
        }
}

// ---------------------------------------------------------------------------
// GEMM2: out[M,N](fp32) = (Aoh+Aol)[M,K] @ (Bh+Bl)[N,K]^T + bias, 3-term.
// ---------------------------------------------------------------------------
__global__ __launch_bounds__(256) void gemm_ao_kernel(
    const unsigned short* __restrict__ Aoh,
    const unsigned short* __restrict__ Aol,
    const unsigned short* __restrict__ Bth,
    const unsigned short* __restrict__ Btl,
    const float* __restrict__ bias,
    float* __restrict__ C, int M, int N, int K)
{
    __shared__ __align__(16) unsigned short Ah[128][ASTRIDE];
    __shared__ __align__(16) unsigned short Al[128][ASTRIDE];
    __shared__ __align__(16) unsigned short Bh[128][ASTRIDE];
    __shared__ __align__(16) unsigned short Bl[128][ASTRIDE];

    const int tid  = threadIdx.x;
    const int wave = tid >> 6;
    const int lane = tid & 63;
    const int col  = lane & 15;
    const int q4   = lane >> 4;
    const int wm   = (wave >> 1) * 64;
    const int wn   = (wave & 1) * 64;

    const int nwg = gridDim.x;
    const int cpx = nwg >> 3;
    const int swz = (blockIdx.x & 7) * cpx + (blockIdx.x >> 3);
    const int nbn = N / 128;
    const int bm = (swz / nbn) * 128;
    const int bn = (swz % nbn) * 128;

    const int sr = tid >> 1;
    const int sq = (tid & 1) * 16;
    const unsigned short* ahp = Aoh + (size_t)(bm + sr) * K + sq;
    const unsigned short* alp = Aol + (size_t)(bm + sr) * K + sq;
    const unsigned short* bhp = Bth + (size_t)(bn + sr) * K + sq;
    const unsigned short* blp = Btl + (size_t)(bn + sr) * K + sq;

    f32x4 acc[4][4];
#pragma unroll
    for (int i = 0; i < 4; ++i)
#pragma unroll
        for (int j = 0; j < 4; ++j) acc[i][j] = (f32x4){0.f, 0.f, 0.f, 0.f};

    short8v a0h, a1h, a0l, a1l, b0h, b1h, b0l, b1l;

#define G2LOAD(k0) { \
    a0h = *(const short8v*)(ahp + (k0)); \
    a1h = *(const short8v*)(ahp + (k0) + 8); \
    a0l = *(const short8v*)(alp + (k0)); \
    a1l = *(const short8v*)(alp + (k0) + 8); \
    b0h = *(const short8v*)(bhp + (k0)); \
    b1h = *(const short8v*)(bhp + (k0) + 8); \
    b0l = *(const short8v*)(blp + (k0)); \
    b1l = *(const short8v*)(blp + (k0) + 8); \
}

#define G2WRITE() { \
    *(short8v*)&Ah[sr][sq]     = a0h; \
    *(short8v*)&Ah[sr][sq + 8] = a1h; \
    *(short8v*)&Al[sr][sq]     = a0l; \
    *(short8v*)&Al[sr][sq + 8] = a1l; \
    *(short8v*)&Bh[sr][sq]     = b0h; \
    *(short8v*)&Bh[sr][sq + 8] = b1h; \
    *(short8v*)&Bl[sr][sq]     = b0l; \
    *(short8v*)&Bl[sr][sq + 8] = b1l; \
}

#define G2COMP() { \
    short8v ahf[4], alf[4]; \
    _Pragma("unroll") \
    for (int mt = 0; mt < 4; ++mt) { \
        ahf[mt] = *(const short8v*)&Ah[wm + mt * 16 + col][q4 * 8]; \
        alf[mt] = *(const short8v*)&Al[wm + mt * 16 + col][q4 * 8]; \
    } \
    _Pragma("unroll") \
    for (int nt = 0; nt < 4; ++nt) { \
        short8v bhf = *(const short8v*)&Bh[wn + nt * 16 + col][q4 * 8]; \
        short8v blf = *(const short8v*)&Bl[wn + nt * 16 + col][q4 * 8]; \
        _Pragma("unroll") \
        for (int mt = 0; mt < 4; ++mt) { \
            acc[mt][nt] = __builtin_amdgcn_mfma_f32_16x16x32_bf16(ahf[mt], bhf, acc[mt][nt], 0, 0, 0); \
            acc[mt][nt] = __builtin_amdgcn_mfma_f32_16x16x32_bf16(alf[mt], bhf, acc[mt][nt], 0, 0, 0); \
            acc[mt][nt] = __builtin_amdgcn_mfma_f32_16x16x32_bf16(ahf[mt], blf, acc[mt][nt], 0, 0, 0); \
        } \
    } \
}

    G2LOAD(0);
    G2WRITE();
    for (int k0 = 32; k0 < K; k0 += 32) {
        G2LOAD(k0);
        __syncthreads();
        G2COMP();
        __syncthreads();
        G2WRITE();
    }
    __syncthreads();
    G2COMP();
#undef G2LOAD
#undef G2WRITE
#undef G2COMP

    float bv[4];
#pragma unroll
    for (int nt = 0; nt < 4; ++nt) bv[nt] = bias[bn + wn + nt * 16 + col];

#pragma unroll
    for (int mt = 0; mt < 4; ++mt)
#pragma unroll
        for (int r = 0; r < 4; ++r) {
            const int row = bm + wm + mt * 16 + q4 * 4 + r;
#pragma unroll
            for (int nt = 0; nt < 4; ++nt)
                C[(size_t)row * N + bn + wn + nt * 16 + col] = acc[mt][nt][r] + bv[nt];
        }
}

// ---------------------------------------------------------------------------
// MFMA flash attention — exact R15 structure (best measured: 72 µs attn,
// 155.7 µs total). 256-thread blocks (4 waves, 128 q-rows), KBLK=64,
// fixed-max softmax, permlane P-exchange, tree-sum, T14 pipeline rotation.
// No setprio (R18 showed it regresses this barrier-synced kernel).
// ---------------------------------------------------------------------------
__global__ __launch_bounds__(256) void attn_mfma_kernel(
    const unsigned short* __restrict__ qkv,
    unsigned short* __restrict__ aoh, unsigned short* __restrict__ aol)
{
    __shared__ __align__(16) unsigned short Ks[64 * 64];   // [key][dim] swizzled
    __shared__ __align__(16) unsigned short Vt[64 * 64];   // [dim][key] swizzled

    const int tid  = threadIdx.x;
    const int wave = tid >> 6;           // 0..3
    const int lane = tid & 63;
    const int l31  = lane & 31;
    const int lh   = lane >> 5;

    const int bh = blockIdx.x;           // b*16 + h
    const int qt = blockIdx.y;           // 0..15 (128 q-rows per block)
    const int b = bh >> 4;
    const int h = bh & 15;
    const int qrow0 = b * SEQ + qt * 128 + wave * 32;
    const int krow0 = b * SEQ;

    // ---- permlane32_swap semantic probe (wave-uniform flag) ----
    bool s1;
    {
        int ta = lane, tb = 4096 + lane;
        asm volatile("v_permlane32_swap_b32 %0, %1" : "+v"(ta), "+v"(tb));
        s1 = __all((lane < 32) ? (ta == lane) : (ta == 4096 + lane - 32));
    }

    // Q fragments (B-operand), pre-scaled by C2F in GEMM1
    short8v qf[4];
    {
        const unsigned short* qsrc = qkv + (size_t)(qrow0 + l31) * (3 * D_MODEL) + h * 64 + lh * 8;
#pragma unroll
        for (int s = 0; s < 4; ++s)
            qf[s] = *(const short8v*)(qsrc + s * 16);
    }

    // staging indices (256 threads)
    const int krow = tid >> 2;           // 0..63
    const int koff = (tid & 3) * 16;     // 0,16,32,48
    const int vk0  = (tid & 31) * 2;     // 2 keys
    const int vd0  = (tid >> 5) * 8;     // 8 dims

    // running chunk pointers (advance by 64 rows per chunk)
    const unsigned short* kp = qkv + (size_t)(krow0 + krow) * (3 * D_MODEL)
                               + D_MODEL + h * 64 + koff;
    const unsigned short* vp = qkv + (size_t)(krow0 + vk0) * (3 * D_MODEL)
                               + 2 * D_MODEL + h * 64 + vd0;
    const ptrdiff_t CSTRIDE = (ptrdiff_t)64 * 3 * D_MODEL;

    f32x16 ot0, ot1;
#pragma unroll
    for (int r = 0; r < 16; ++r) { ot0[r] = 0.f; ot1[r] = 0.f; }
    float ll = 0.f;

    short8v kg[2], vg[2];
    const int swr = (l31 & 7) << 3;

#define PLSWAP(a, b) asm volatile("v_permlane32_swap_b32 %0, %1" : "+v"(a), "+v"(b))

#define ALOAD() { \
    kg[0] = ((const short8v*)kp)[0]; \
    kg[1] = ((const short8v*)kp)[1]; \
    vg[0] = *(const short8v*)(vp); \
    vg[1] = *(const short8v*)(vp + 3 * D_MODEL); \
    kp += CSTRIDE; vp += CSTRIDE; \
}

#define AWRITE() { \
    const int base = krow * 64 + koff; \
    const int sw = (krow & 7) << 3; \
    *(short8v*)&Ks[(base)     ^ sw] = kg[0]; \
    *(short8v*)&Ks[(base + 8) ^ sw] = kg[1]; \
    _Pragma("unroll") \
    for (int j = 0; j < 8; ++j) { \
        ushort2 w; \
        w.x = ((const unsigned short*)&vg[0])[j]; \
        w.y = ((const unsigned short*)&vg[1])[j]; \
        const int d = vd0 + j; \
        *(ushort2*)&Vt[(d * 64 + vk0) ^ ((d & 7) << 3)] = w; \
    } \
}

#define ACOMPUTE() { \
    f32x16 st0, st1; \
    _Pragma("unroll") for (int r = 0; r < 16; ++r) { st0[r] = 0.f; st1[r] = 0.f; } \
    _Pragma("unroll") \
    for (int s = 0; s < 4; ++s) { \
        short8v kf0 = *(const short8v*)&Ks[(l31 * 64 + s * 16 + lh * 8) ^ swr]; \
        st0 = __builtin_amdgcn_mfma_f32_32x32x16_bf16(kf0, qf[s], st0, 0, 0, 0); \
    } \
    _Pragma("unroll") \
    for (int s = 0; s < 4; ++s) { \
        short8v kf1 = *(const short8v*)&Ks[((32 + l31) * 64 + s * 16 + lh * 8) ^ swr]; \
        st1 = __builtin_amdgcn_mfma_f32_32x32x16_bf16(kf1, qf[s], st1, 0, 0, 0); \
    } \
    _Pragma("unroll") \
    for (int r = 0; r < 16; ++r) { \
        st0[r] = __builtin_exp2f(st0[r]); \
        st1[r] = __builtin_exp2f(st1[r]); \
    } \
    { \
        float a0 = (st0[0] + st0[1]) + (st0[2] + st0[3]); \
        float a1 = (st0[4] + st0[5]) + (st0[6] + st0[7]); \
        float a2 = (st0[8] + st0[9]) + (st0[10] + st0[11]); \
        float a3 = (st0[12] + st0[13]) + (st0[14] + st0[15]); \
        float b0 = (st1[0] + st1[1]) + (st1[2] + st1[3]); \
        float b1 = (st1[4] + st1[5]) + (st1[6] + st1[7]); \
        float b2 = (st1[8] + st1[9]) + (st1[10] + st1[11]); \
        float b3 = (st1[12] + st1[13]) + (st1[14] + st1[15]); \
        float rs = ((a0 + a1) + (a2 + a3)) + ((b0 + b1) + (b2 + b3)); \
        rs += __shfl_xor(rs, 32); \
        ll += rs; \
    } \
    unsigned int pk[16]; \
    _Pragma("unroll") \
    for (int i2 = 0; i2 < 8; ++i2) { \
        pk[i2]     = cvtpk(st0[2 * i2], st0[2 * i2 + 1]); \
        pk[8 + i2] = cvtpk(st1[2 * i2], st1[2 * i2 + 1]); \
    } \
    if (s1) { \
        PLSWAP(pk[0], pk[2]);   PLSWAP(pk[1], pk[3]); \
        PLSWAP(pk[4], pk[6]);   PLSWAP(pk[5], pk[7]); \
        PLSWAP(pk[8], pk[10]);  PLSWAP(pk[9], pk[11]); \
        PLSWAP(pk[12], pk[14]); PLSWAP(pk[13], pk[15]); \
    } else { \
        PLSWAP(pk[2], pk[0]);   PLSWAP(pk[3], pk[1]); \
        PLSWAP(pk[6], pk[4]);   PLSWAP(pk[7], pk[5]); \
        PLSWAP(pk[10], pk[8]);  PLSWAP(pk[11], pk[9]); \
        PLSWAP(pk[14], pk[12]); PLSWAP(pk[15], pk[13]); \
    } \
    u32x4 pf[4]; \
    pf[0].x = pk[0];  pf[0].y = pk[1];  pf[0].z = pk[2];  pf[0].w = pk[3]; \
    pf[1].x = pk[4];  pf[1].y = pk[5];  pf[1].z = pk[6];  pf[1].w = pk[7]; \
    pf[2].x = pk[8];  pf[2].y = pk[9];  pf[2].z = pk[10]; pf[2].w = pk[11]; \
    pf[3].x = pk[12]; pf[3].y = pk[13]; pf[3].z = pk[14]; pf[3].w = pk[15]; \
    _Pragma("unroll") \
    for (int ks2 = 0; ks2 < 4; ++ks2) { \
        const short8v pfr = u2s(pf[ks2]); \
        const int keyoff = ks2 * 16 + lh * 8; \
        short8v vf0 = *(const short8v*)&Vt[(l31 * 64 + keyoff) ^ swr]; \
        ot0 = __builtin_amdgcn_mfma_f32_32x32x16_bf16(vf0, pfr, ot0, 0, 0, 0); \
        short8v vf1 = *(const short8v*)&Vt[((32 + l31) * 64 + keyoff) ^ swr]; \
        ot1 = __builtin_amdgcn_mfma_f32_32x32x16_bf16(vf1, pfr, ot1, 0, 0, 0); \
    } \
}

    // ---- software pipeline (R12 schedule) ----
    ALOAD();                     // chunk 0
    AWRITE();
    for (int i = 0; i < 31; ++i) {
        ALOAD();                 // chunk i+1, in flight during compute of i
        __syncthreads();         // writes of chunk i visible
        ACOMPUTE();              // chunk i
        __syncthreads();         // all reads of chunk i done
        AWRITE();                // chunk i+1 (loads landed during compute)
    }
    __syncthreads();
    ACOMPUTE();                  // chunk 31
#undef ALOAD
#undef AWRITE
#undef ACOMPUTE
#undef PLSWAP

    // ---- finalize: lane holds q = l31; O^T rows are dims ----
    const float il = 1.0f / ll;
    const int qrow = qrow0 + l31;
    unsigned short* dh = aoh + (size_t)qrow * D_MODEL + h * 64;
    unsigned short* dl = aol + (size_t)qrow * D_MODEL + h * 64;
#pragma unroll
    for (int r = 0; r < 16; ++r) {
        const int dloc = (r & 3) + 8 * (r >> 2) + 4 * lh;
        unsigned short hh, lo2;
        split_bf(ot0[r] * il, hh, lo2);
        dh[dloc] = hh; dl[dloc] = lo2;
        split_bf(ot1[r] * il, hh, lo2);
        dh[32 + dloc] = hh; dl[32 + dloc] = lo2;
    }
}

// ---------------------------------------------------------------------------
extern "C" void kernel_launch(void* const* d_in, const int* in_sizes, int n_in,
                              void* d_out, int out_size, void* d_ws, size_t ws_size,
                              hipStream_t stream) {
    (void)in_sizes; (void)n_in; (void)out_size; (void)ws_size;

    const float* x     = (const float*)d_in[0];
    const float* w_qkv = (const float*)d_in[1];
    const float* b_qkv = (const float*)d_in[2];
    const float* w_out = (const float*)d_in[3];
    const float* b_out = (const float*)d_in[4];
    float* out = (float*)d_out;

    char* ws = (char*)d_ws;
    unsigned short* qkv_bf  = (unsigned short*)(ws);                   // 25,165,824
    unsigned short* aoh     = (unsigned short*)(ws + 25165824);        //  8,388,608
    unsigned short* aol     = (unsigned short*)(ws + 33554432);        //  8,388,608
    unsigned short* wqkvT_h = (unsigned short*)(ws + 41943040);        //  6,291,456
    unsigned short* woutT_h = (unsigned short*)(ws + 48234496);        //  2,097,152
    unsigned short* woutT_l = (unsigned short*)(ws + 50331648);        //  2,097,152
    // end: 52,428,800 B

    // 1) fused weight prep (one launch): w_qkv RNE (Q cols scaled), w_out split
    {
        const int nq = (D_MODEL / 64) * (3 * D_MODEL / 64);   // 768
        const int no = (D_MODEL / 64) * (D_MODEL / 64);       // 256
        weightprep_kernel<<<dim3(nq + no), 256, 0, stream>>>(
            w_qkv, wqkvT_h, w_out, woutT_h, woutT_l, nq);
    }

    // 2) QKV projection (1-term bf16)
    gemm_xw_kernel<<<dim3((NROWS / 128) * (3 * D_MODEL / 128)), 256, 0, stream>>>(
        x, wqkvT_h, b_qkv, qkv_bf, NROWS, 3 * D_MODEL, D_MODEL, D_MODEL);

    // 3) flash attention (R15 structure, no setprio)
    attn_mfma_kernel<<<dim3(NBATCH * N_HEADS, SEQ / 128), 256, 0, stream>>>(qkv_bf, aoh, aol);

    // 4) output projection (3-term)
    gemm_ao_kernel<<<dim3((NROWS / 128) * (D_MODEL / 128)), 256, 0, stream>>>(
        aoh, aol, woutT_h, woutT_l, b_out, out, NROWS, D_MODEL, D_MODEL);
}